// Round 1
// baseline (1113.878 us; speedup 1.0000x reference)
//
#include <hip/hip_runtime.h>

#define FEATS 64

// Phase 1: per-edge scatter. 16 threads per edge, each handling a float4 of
// the 64-wide feature row. Consecutive threads read consecutive float4s of
// feature[src[e]] (256 B contiguous per edge group). atomicAdd on global
// fp32 is device-scope on gfx950 (cross-XCD safe).
__global__ void edge_scatter(const float* __restrict__ feature,
                             const float* __restrict__ degree,
                             const int* __restrict__ src,
                             const int* __restrict__ dst,
                             float* __restrict__ agg, int n_edges) {
    int t = blockIdx.x * blockDim.x + threadIdx.x;
    int e = t >> 4;
    if (e >= n_edges) return;
    int f = (t & 15) << 2;
    int s = src[e];
    int d = dst[e];
    float w = rsqrtf(degree[s]);
    const float4 v = *reinterpret_cast<const float4*>(feature + (size_t)s * FEATS + f);
    float* o = agg + (size_t)d * FEATS + f;
    atomicAdd(o + 0, v.x * w);
    atomicAdd(o + 1, v.y * w);
    atomicAdd(o + 2, v.z * w);
    atomicAdd(o + 3, v.w * w);
}

// Phase 2: out[n] = (agg[n] * rsqrt(deg[n])) @ W + b.
// Each thread owns output column o = tid&63 and keeps W[:,o] in 64 VGPRs.
// Each wave processes one node per iteration: lanes load the scaled agg row
// (coalesced 256 B), stage in LDS, then broadcast-read per-k (same-address
// LDS reads broadcast for free). No __syncthreads needed: each wave touches
// only its own sA row.
__global__ __launch_bounds__(256) void node_apply(
        const float* __restrict__ agg,
        const float* __restrict__ degree,
        const float* __restrict__ Wm,
        const float* __restrict__ bias,
        float* __restrict__ out, int n_nodes) {
    const int o  = threadIdx.x & 63;
    const int wv = threadIdx.x >> 6;  // wave id 0..3

    float wreg[FEATS];
#pragma unroll
    for (int k = 0; k < FEATS; ++k) wreg[k] = Wm[k * FEATS + o];  // coalesced across lanes
    const float bo = bias[o];

    __shared__ float sA[4][FEATS];

    for (int n = blockIdx.x * 4 + wv; n < n_nodes; n += gridDim.x * 4) {
        const float inv_s = rsqrtf(degree[n]);
        sA[wv][o] = agg[(size_t)n * FEATS + o] * inv_s;
        float acc = bo;
#pragma unroll
        for (int k = 0; k < FEATS; ++k) acc = fmaf(sA[wv][k], wreg[k], acc);
        out[(size_t)n * FEATS + o] = acc;
    }
}

extern "C" void kernel_launch(void* const* d_in, const int* in_sizes, int n_in,
                              void* d_out, int out_size, void* d_ws, size_t ws_size,
                              hipStream_t stream) {
    const float* feature = (const float*)d_in[0];
    const float* degree  = (const float*)d_in[1];
    const int*   src     = (const int*)d_in[2];
    const int*   dst     = (const int*)d_in[3];
    const float* Wm      = (const float*)d_in[4];
    const float* bias    = (const float*)d_in[5];
    float* out = (float*)d_out;
    float* agg = (float*)d_ws;  // n_nodes * 64 fp32 = 19.2 MB scratch

    const int n_nodes = in_sizes[1];
    const int n_edges = in_sizes[2];

    // agg must be zeroed every call (ws re-poisoned to 0xAA).
    hipMemsetAsync(agg, 0, (size_t)n_nodes * FEATS * sizeof(float), stream);

    const int threads1 = 256;
    const int blocks1 = (n_edges * 16 + threads1 - 1) / threads1;  // 16 threads/edge
    edge_scatter<<<blocks1, threads1, 0, stream>>>(feature, degree, src, dst, agg, n_edges);

    node_apply<<<2048, 256, 0, stream>>>(agg, degree, Wm, bias, out, n_nodes);
}

// Round 2
// 256.089 us; speedup vs baseline: 4.3496x; 4.3496x over previous
//
#include <hip/hip_runtime.h>

#define FEATS 64

// ---------------------------------------------------------------------------
// Atomic-free "pull" formulation.
// degree[n] == in_degree(n) + 1 exactly (reference builds it from bincount),
// so per-node bucket counts are known without a histogram pass.
// Pipeline: scan(3 kernels) -> fill buckets (1.2M int atomics) -> per-node
// gather (coalesced 256B feature rows, L3-resident) -> GEMM apply.
// ---------------------------------------------------------------------------

// Kernel 1: per-block exclusive scan of cnt[i] = (int)degree[i]-1.
// Also computes winv[i] = rsqrt(degree[i]) (free ride, saves a launch).
__global__ __launch_bounds__(1024) void scan1(const float* __restrict__ degree,
                                              int* __restrict__ scanned,
                                              int* __restrict__ bsum,
                                              float* __restrict__ winv,
                                              int n) {
    __shared__ int tmp[1024];
    const int tid = threadIdx.x;
    const int i = blockIdx.x * 1024 + tid;
    int x = 0;
    if (i < n) {
        float dg = degree[i];
        winv[i] = rsqrtf(dg);
        x = (int)(dg + 0.5f) - 1;
    }
    tmp[tid] = x;
    __syncthreads();
    // Hillis-Steele inclusive scan
#pragma unroll
    for (int o = 1; o < 1024; o <<= 1) {
        int v = (tid >= o) ? tmp[tid - o] : 0;
        __syncthreads();
        tmp[tid] += v;
        __syncthreads();
    }
    if (i < n) scanned[i] = tmp[tid] - x;      // exclusive within block
    if (tid == 1023) bsum[blockIdx.x] = tmp[1023];
}

// Kernel 2: exclusive scan of the (<=128) block sums, single block.
__global__ __launch_bounds__(128) void scan2(const int* __restrict__ bsum,
                                             int* __restrict__ boff, int nb) {
    __shared__ int tmp[128];
    const int tid = threadIdx.x;
    int x = (tid < nb) ? bsum[tid] : 0;
    tmp[tid] = x;
    __syncthreads();
#pragma unroll
    for (int o = 1; o < 128; o <<= 1) {
        int v = (tid >= o) ? tmp[tid - o] : 0;
        __syncthreads();
        tmp[tid] += v;
        __syncthreads();
    }
    boff[tid] = tmp[tid] - x;
}

// Kernel 3: add block offsets -> global exclusive offsets.
__global__ __launch_bounds__(1024) void scan3(const int* __restrict__ scanned,
                                              const int* __restrict__ boff,
                                              int* __restrict__ off, int n) {
    const int i = blockIdx.x * 1024 + threadIdx.x;
    if (i < n) off[i] = scanned[i] + boff[blockIdx.x];
}

// Kernel 4: bucket-fill. One thread per edge; 1.2M int atomics (vs 76.8M fp32
// before). After this kernel, off[n] == bucket_end(n); gather recovers
// start = end - cnt.
__global__ __launch_bounds__(256) void fill(const int* __restrict__ src,
                                            const int* __restrict__ dst,
                                            int* __restrict__ off,
                                            int* __restrict__ esrc, int n_edges) {
    const int e = blockIdx.x * blockDim.x + threadIdx.x;
    if (e >= n_edges) return;
    const int pos = atomicAdd(&off[dst[e]], 1);
    esrc[pos] = src[e];
}

// Kernel 5: per-node gather. One wave per node; lane = feature column.
// Each edge is one coalesced 256B read of feature[s]; feature (19.2MB) is
// L3-resident. 2-way unroll for two outstanding loads per lane.
// Writes agg already scaled by BOTH normalization factors.
__global__ __launch_bounds__(256) void gather(const float* __restrict__ feature,
                                              const float* __restrict__ degree,
                                              const float* __restrict__ winv,
                                              const int* __restrict__ off,
                                              const int* __restrict__ esrc,
                                              float* __restrict__ agg, int n_nodes) {
    const int n = blockIdx.x * 4 + (threadIdx.x >> 6);
    if (n >= n_nodes) return;
    const int lane = threadIdx.x & 63;
    const int end = off[n];                       // post-fill == bucket end
    const int cnt = (int)(degree[n] + 0.5f) - 1;
    int j = end - cnt;
    float acc0 = 0.f, acc1 = 0.f;
    for (; j + 1 < end; j += 2) {
        const int s0 = esrc[j];
        const int s1 = esrc[j + 1];
        const float f0 = feature[(size_t)s0 * FEATS + lane];
        const float f1 = feature[(size_t)s1 * FEATS + lane];
        acc0 = fmaf(f0, winv[s0], acc0);
        acc1 = fmaf(f1, winv[s1], acc1);
    }
    if (j < end) {
        const int s0 = esrc[j];
        acc0 = fmaf(feature[(size_t)s0 * FEATS + lane], winv[s0], acc0);
    }
    agg[(size_t)n * FEATS + lane] = (acc0 + acc1) * winv[n];
}

// Kernel 6: out[n] = agg[n] @ W + b. Thread owns output column o, W[:,o] in
// 64 VGPRs; A-row staged in LDS, broadcast reads (same-address = free).
__global__ __launch_bounds__(256) void node_apply(
        const float* __restrict__ agg,
        const float* __restrict__ Wm,
        const float* __restrict__ bias,
        float* __restrict__ out, int n_nodes) {
    const int o  = threadIdx.x & 63;
    const int wv = threadIdx.x >> 6;

    float wreg[FEATS];
#pragma unroll
    for (int k = 0; k < FEATS; ++k) wreg[k] = Wm[k * FEATS + o];
    const float bo = bias[o];

    __shared__ float sA[4][FEATS];

    for (int n = blockIdx.x * 4 + wv; n < n_nodes; n += gridDim.x * 4) {
        sA[wv][o] = agg[(size_t)n * FEATS + o];
        float acc = bo;
#pragma unroll
        for (int k = 0; k < FEATS; ++k) acc = fmaf(sA[wv][k], wreg[k], acc);
        out[(size_t)n * FEATS + o] = acc;
    }
}

static inline size_t align256(size_t x) { return (x + 255) & ~(size_t)255; }

extern "C" void kernel_launch(void* const* d_in, const int* in_sizes, int n_in,
                              void* d_out, int out_size, void* d_ws, size_t ws_size,
                              hipStream_t stream) {
    const float* feature = (const float*)d_in[0];
    const float* degree  = (const float*)d_in[1];
    const int*   src     = (const int*)d_in[2];
    const int*   dst     = (const int*)d_in[3];
    const float* Wm      = (const float*)d_in[4];
    const float* bias    = (const float*)d_in[5];
    float* out = (float*)d_out;

    const int n_nodes = in_sizes[1];
    const int n_edges = in_sizes[2];
    const int NB = (n_nodes + 1023) / 1024;      // 74 for N=75000 (<=128)

    // Workspace layout (~24.6 MB total)
    char* ws = (char*)d_ws;
    float* winv   = (float*)ws;               ws += align256((size_t)n_nodes * 4);
    int*   scannd = (int*)ws;                 ws += align256((size_t)n_nodes * 4);
    int*   off    = (int*)ws;                 ws += align256((size_t)n_nodes * 4);
    int*   bsum   = (int*)ws;                 ws += align256(128 * 4);
    int*   boff   = (int*)ws;                 ws += align256(128 * 4);
    int*   esrc   = (int*)ws;                 ws += align256((size_t)n_edges * 4);
    float* agg    = (float*)ws;               ws += align256((size_t)n_nodes * FEATS * 4);

    scan1<<<NB, 1024, 0, stream>>>(degree, scannd, bsum, winv, n_nodes);
    scan2<<<1, 128, 0, stream>>>(bsum, boff, NB);
    scan3<<<NB, 1024, 0, stream>>>(scannd, boff, off, n_nodes);
    fill<<<(n_edges + 255) / 256, 256, 0, stream>>>(src, dst, off, esrc, n_edges);
    gather<<<(n_nodes + 3) / 4, 256, 0, stream>>>(feature, degree, winv, off, esrc, agg, n_nodes);
    node_apply<<<2048, 256, 0, stream>>>(agg, Wm, bias, out, n_nodes);
}

// Round 3
// 215.523 us; speedup vs baseline: 5.1683x; 1.1882x over previous
//
#include <hip/hip_runtime.h>

#define FEATS 64
#define PSZ   64          // nodes per partition
#define MAXP  1216        // >= ceil(75000/64) = 1172
#define CAP   1536        // LDS bucket capacity (mean 1024, +16 sigma) — guarded fallback below
#define PSCH  4688        // edges per pscatter block = ceil(1.2M/256)
#define PEPT  19          // edges per thread in pscatter = ceil(PSCH/256)

// ---------------------------------------------------------------------------
// K1: winv[n] = rsqrt(degree), Fs[n] = feature[n] * winv[n] (kills the per-edge
// dependent winv[src] load), part_total[p] = sum of in-degrees in partition p
// (exact, from degree == indeg+1 — no histogram needed).
// ---------------------------------------------------------------------------
__global__ __launch_bounds__(256) void prep(const float* __restrict__ degree,
                                            const float* __restrict__ feature,
                                            float* __restrict__ winv,
                                            float* __restrict__ Fs,
                                            int* __restrict__ part_total,
                                            int n_nodes) {
    __shared__ float swv[PSZ];
    const int p = blockIdx.x;
    const int n0 = p * PSZ;
    const int nn = min(PSZ, n_nodes - n0);
    const int tid = threadIdx.x;
    int c = 0;
    if (tid < nn) {
        float dg = degree[n0 + tid];
        float w = rsqrtf(dg);
        winv[n0 + tid] = w;
        swv[tid] = w;
        c = (int)(dg + 0.5f) - 1;
    }
    if (tid < 64) {   // wave 0 reduces partition edge count
#pragma unroll
        for (int off = 32; off > 0; off >>= 1) c += __shfl_down(c, off);
        if (tid == 0) part_total[p] = c;
    }
    __syncthreads();
    const float4* fin = (const float4*)(feature + (size_t)n0 * FEATS);
    float4* fo = (float4*)(Fs + (size_t)n0 * FEATS);
    const int nv = nn * (FEATS / 4);          // 16 float4 per row
    for (int i = tid; i < nv; i += 256) {
        float w = swv[i >> 4];
        float4 v = fin[i];
        v.x *= w; v.y *= w; v.z *= w; v.w *= w;
        fo[i] = v;
    }
}

// ---------------------------------------------------------------------------
// K2: exclusive scan of part_total -> slab offsets (exact capacities); zero the
// per-partition reservation counters.
// ---------------------------------------------------------------------------
__global__ __launch_bounds__(1024) void scanP(const int* __restrict__ part_total,
                                              int* __restrict__ part_off,
                                              int* __restrict__ gcnt, int np) {
    __shared__ int tmp[1024];
    const int t = threadIdx.x;
    const int e0 = 2 * t, e1 = 2 * t + 1;
    int a = (e0 < np) ? part_total[e0] : 0;
    int b = (e1 < np) ? part_total[e1] : 0;
    int s = a + b;
    tmp[t] = s;
    __syncthreads();
#pragma unroll
    for (int o = 1; o < 1024; o <<= 1) {
        int v = (t >= o) ? tmp[t - o] : 0;
        __syncthreads();
        tmp[t] += v;
        __syncthreads();
    }
    const int excl = tmp[t] - s;
    if (e0 < np) part_off[e0] = excl;
    if (e1 < np) part_off[e1] = excl + a;
    for (int i = t; i < np; i += 1024) gcnt[i] = 0;
}

// ---------------------------------------------------------------------------
// K3: partition-scatter. Per-edge work uses ONLY LDS atomics; one global
// atomic per (block, partition) reserves slab space; staged LDS reorder makes
// the slab writes coalesced runs. Record = src | (dst&63)<<17 (23 bits).
// ---------------------------------------------------------------------------
__global__ __launch_bounds__(256) void pscatter(const int* __restrict__ src,
                                                const int* __restrict__ dst,
                                                const int* __restrict__ part_off,
                                                int* __restrict__ gcnt,
                                                int* __restrict__ slab,
                                                int n_edges, int np) {
    __shared__ int cnt[MAXP];
    __shared__ int loc[MAXP];
    __shared__ int sbase[MAXP];
    __shared__ int ssum[256];
    __shared__ int sval[PEPT * 256];
    __shared__ int saddr[PEPT * 256];
    const int tid = threadIdx.x;
    const int estart = blockIdx.x * PSCH;
    const int eend = min(estart + PSCH, n_edges);
    for (int i = tid; i < np; i += 256) cnt[i] = 0;
    __syncthreads();
    int prk[PEPT];
#pragma unroll
    for (int k = 0; k < PEPT; ++k) {
        const int e = estart + tid + k * 256;
        prk[k] = -1;
        if (e < eend) {
            const int p = dst[e] >> 6;                 // PSZ = 64
            const int r = atomicAdd(&cnt[p], 1);       // LDS atomic
            prk[k] = p | (r << 11);                    // p<2048(11b), r<8192(13b)
        }
    }
    __syncthreads();
    // scan cnt[0..np) with 256 threads (<=5 parts per thread)
    int psum = 0;
    int my[5];
    const int p0 = tid * 5;
#pragma unroll
    for (int j = 0; j < 5; ++j) {
        const int p = p0 + j;
        const int c = (p < np) ? cnt[p] : 0;
        my[j] = psum;
        psum += c;
    }
    ssum[tid] = psum;
    __syncthreads();
#pragma unroll
    for (int o = 1; o < 256; o <<= 1) {
        int v = (tid >= o) ? ssum[tid - o] : 0;
        __syncthreads();
        ssum[tid] += v;
        __syncthreads();
    }
    const int tbase = ssum[tid] - psum;
#pragma unroll
    for (int j = 0; j < 5; ++j) {
        const int p = p0 + j;
        if (p < np) loc[p] = tbase + my[j];
    }
    __syncthreads();
    // one global atomic per (block, partition)
    for (int i = tid; i < np; i += 256) {
        const int c = cnt[i];
        if (c > 0) sbase[i] = atomicAdd(&gcnt[i], c);
    }
    __syncthreads();
#pragma unroll
    for (int k = 0; k < PEPT; ++k) {
        const int e = estart + tid + k * 256;
        if (e < eend) {
            const int pr = prk[k];
            const int p = pr & 2047;
            const int r = pr >> 11;
            const int idx = loc[p] + r;
            sval[idx]  = src[e] | ((dst[e] & 63) << 17);
            saddr[idx] = part_off[p] + sbase[p] + r;
        }
    }
    __syncthreads();
    const int m = eend - estart;
    for (int i = tid; i < m; i += 256) slab[saddr[i]] = sval[i];  // coalesced runs
}

// ---------------------------------------------------------------------------
// K4: per-partition bucket (LDS atomics) -> per-node gather of Fs rows ->
// fused GEMM epilogue (W columns in VGPRs, cross-lane via readlane/shfl).
// ---------------------------------------------------------------------------
__global__ __launch_bounds__(256) void gather_apply(const int* __restrict__ slab,
                                                    const int* __restrict__ part_off,
                                                    const float* __restrict__ degree,
                                                    const float* __restrict__ winv,
                                                    const float* __restrict__ Fs,
                                                    const float* __restrict__ Wm,
                                                    const float* __restrict__ bias,
                                                    float* __restrict__ out,
                                                    int n_nodes) {
    __shared__ int boff[PSZ + 1];
    __shared__ int bcur[PSZ];
    __shared__ int ledges[CAP];
    const int tid = threadIdx.x;
    const int lane = tid & 63;
    const int wv = tid >> 6;
    const int p = blockIdx.x;
    const int n0 = p * PSZ;
    const int nn = min(PSZ, n_nodes - n0);

    float wreg[FEATS];
#pragma unroll
    for (int k = 0; k < FEATS; ++k) wreg[k] = Wm[k * FEATS + lane];  // W[:,lane]
    const float bo = bias[lane];

    if (tid < PSZ) bcur[tid] = 0;
    if (wv == 0) {   // wave-0 shuffle scan of per-node counts
        int c = (lane < nn) ? ((int)(degree[n0 + lane] + 0.5f) - 1) : 0;
        int x = c;
#pragma unroll
        for (int off = 1; off < 64; off <<= 1) {
            int v = __shfl_up(x, off);
            if (lane >= off) x += v;
        }
        if (lane == 0) boff[0] = 0;
        boff[lane + 1] = x;              // inclusive
    }
    __syncthreads();
    const int m = boff[PSZ];
    const int s0 = part_off[p];

    if (m <= CAP) {
        for (int i = tid; i < m; i += 256) {
            const int rec = slab[s0 + i];
            const int dl = (rec >> 17) & 63;
            const int pos = boff[dl] + atomicAdd(&bcur[dl], 1);  // LDS atomic
            ledges[pos] = rec & 0x1FFFF;
        }
        __syncthreads();
        for (int n = wv; n < nn; n += 4) {
            const int st = boff[n], en = boff[n + 1];
            float acc0 = 0.f, acc1 = 0.f;
            int j = st;
            for (; j + 3 < en; j += 4) {            // 4 loads in flight
                const int a0 = ledges[j], a1 = ledges[j + 1];
                const int a2 = ledges[j + 2], a3 = ledges[j + 3];
                const float f0 = Fs[(size_t)a0 * FEATS + lane];
                const float f1 = Fs[(size_t)a1 * FEATS + lane];
                const float f2 = Fs[(size_t)a2 * FEATS + lane];
                const float f3 = Fs[(size_t)a3 * FEATS + lane];
                acc0 += f0 + f2;
                acc1 += f1 + f3;
            }
            for (; j < en; ++j) acc0 += Fs[(size_t)ledges[j] * FEATS + lane];
            const float acc = (acc0 + acc1) * winv[n0 + n];  // agg[n][lane]
            float oacc = bo;
#pragma unroll
            for (int k = 0; k < FEATS; ++k)
                oacc = fmaf(__shfl(acc, k), wreg[k], oacc);   // out[n][lane]
            out[(size_t)(n0 + n) * FEATS + lane] = oacc;
        }
    } else {
        // bucket overflow fallback (statistically unreachable, keeps exactness)
        __syncthreads();
        for (int n = wv; n < nn; n += 4) {
            float acc = 0.f;
            for (int i = 0; i < m; ++i) {
                const int rec = slab[s0 + i];
                if (((rec >> 17) & 63) == n)
                    acc += Fs[(size_t)(rec & 0x1FFFF) * FEATS + lane];
            }
            acc *= winv[n0 + n];
            float oacc = bo;
#pragma unroll
            for (int k = 0; k < FEATS; ++k)
                oacc = fmaf(__shfl(acc, k), wreg[k], oacc);
            out[(size_t)(n0 + n) * FEATS + lane] = oacc;
        }
    }
}

static inline size_t align256(size_t x) { return (x + 255) & ~(size_t)255; }

extern "C" void kernel_launch(void* const* d_in, const int* in_sizes, int n_in,
                              void* d_out, int out_size, void* d_ws, size_t ws_size,
                              hipStream_t stream) {
    const float* feature = (const float*)d_in[0];
    const float* degree  = (const float*)d_in[1];
    const int*   src     = (const int*)d_in[2];
    const int*   dst     = (const int*)d_in[3];
    const float* Wm      = (const float*)d_in[4];
    const float* bias    = (const float*)d_in[5];
    float* out = (float*)d_out;

    const int n_nodes = in_sizes[1];
    const int n_edges = in_sizes[2];
    const int np = (n_nodes + PSZ - 1) / PSZ;   // 1172 <= MAXP

    // workspace (~24.3 MB)
    char* ws = (char*)d_ws;
    float* winv       = (float*)ws;  ws += align256((size_t)n_nodes * 4);
    float* Fs         = (float*)ws;  ws += align256((size_t)n_nodes * FEATS * 4);
    int*   part_total = (int*)ws;    ws += align256((size_t)np * 4);
    int*   part_off   = (int*)ws;    ws += align256((size_t)np * 4);
    int*   gcnt       = (int*)ws;    ws += align256((size_t)np * 4);
    int*   slab       = (int*)ws;    ws += align256((size_t)n_edges * 4);

    prep<<<np, 256, 0, stream>>>(degree, feature, winv, Fs, part_total, n_nodes);
    scanP<<<1, 1024, 0, stream>>>(part_total, part_off, gcnt, np);
    const int sblocks = (n_edges + PSCH - 1) / PSCH;
    pscatter<<<sblocks, 256, 0, stream>>>(src, dst, part_off, gcnt, slab, n_edges, np);
    gather_apply<<<np, 256, 0, stream>>>(slab, part_off, degree, winv, Fs, Wm, bias, out, n_nodes);
}